// Round 1
// baseline (476.567 us; speedup 1.0000x reference)
//
#include <hip/hip_runtime.h>
#include <math.h>

// Shapes (fixed by the problem)
#define NCAM 6
#define NHEADS 8
#define NPOINTS 4
#define DD 256
#define HH 20
#define WW 40
#define HWSZ 800            // H*W
#define LQ 4800             // NCAM*HWSZ
#define HDIM 32             // DD/NHEADS

// ---------------------------------------------------------------------------
// Positional encoding: pos[hw][d], d<128 -> y-enc of row, d>=128 -> x-enc of col
__global__ __launch_bounds__(256) void pos_kernel(float* __restrict__ pos) {
    int hw = blockIdx.x;       // 0..799
    int d  = threadIdx.x;      // 0..255
    int h = hw / WW, w = hw % WW;
    int j = (d & 127) >> 1;
    float t = powf(10000.0f, (float)j * (1.0f / 64.0f));
    float v;
    if (d < 128) v = (float)(h + 1) / (20.0f + 1e-6f) * (2.0f * (float)M_PI);
    else         v = (float)(w + 1) / (40.0f + 1e-6f) * (2.0f * (float)M_PI);
    float p = v / t;
    pos[hw * DD + d] = (d & 1) ? cosf(p) : sinf(p);
}

// ---------------------------------------------------------------------------
// Transpose x [6][256][800] -> xt [6][800][256]  (NCHW -> N(HW)C)
__global__ __launch_bounds__(256) void transpose_in(const float* __restrict__ x,
                                                    float* __restrict__ xt) {
    int cam = blockIdx.z;
    int hw0 = blockIdx.x * 32, c0 = blockIdx.y * 32;
    __shared__ float tile[32][33];
    int t = threadIdx.x;
    int lhw = t & 31, lc4 = t >> 5;
#pragma unroll
    for (int i = 0; i < 4; ++i) {
        int lc = lc4 * 4 + i;
        tile[lc][lhw] = x[((size_t)(cam * DD + c0 + lc)) * HWSZ + hw0 + lhw];
    }
    __syncthreads();
    int lc2 = t & 31, lhw4 = t >> 5;
#pragma unroll
    for (int i = 0; i < 4; ++i) {
        int lhw2 = lhw4 * 4 + i;
        xt[((size_t)(cam * HWSZ + hw0 + lhw2)) * DD + c0 + lc2] = tile[lc2][lhw2];
    }
}

// Transpose a [6][800][256] -> o [6][256][800]
__global__ __launch_bounds__(256) void transpose_out(const float* __restrict__ a,
                                                     float* __restrict__ o) {
    int cam = blockIdx.z;
    int hw0 = blockIdx.x * 32, c0 = blockIdx.y * 32;
    __shared__ float tile[32][33];
    int t = threadIdx.x;
    int lc = t & 31, lhw4 = t >> 5;
#pragma unroll
    for (int i = 0; i < 4; ++i) {
        int lhw = lhw4 * 4 + i;
        tile[lhw][lc] = a[((size_t)(cam * HWSZ + hw0 + lhw)) * DD + c0 + lc];
    }
    __syncthreads();
    int lhw2 = t & 31, lc4 = t >> 5;
#pragma unroll
    for (int i = 0; i < 4; ++i) {
        int lc2 = lc4 * 4 + i;
        o[((size_t)(cam * DD + c0 + lc2)) * HWSZ + hw0 + lhw2] = tile[lhw2][lc2];
    }
}

// ---------------------------------------------------------------------------
// Generic fp32 GEMM: C[M,N] = A[M,K=256] @ W[N,K]^T + bias[N]
// mode 0: plain   1: relu   2: conv0 (C=src, C2=src+pos+cam_emb)   3: C += e0 (residual)
#define BM 64
#define BN 64
#define BK 16
__global__ __launch_bounds__(256) void gemm_k256(
    const float* __restrict__ A, const float* __restrict__ Wt,
    const float* __restrict__ bias, float* __restrict__ C, int N, int mode,
    const float* __restrict__ e0, const float* __restrict__ e1,
    float* __restrict__ C2) {
    const int K = 256;
    __shared__ float As[BK][BM + 4];
    __shared__ float Bs[BK][BN + 4];
    int col0 = blockIdx.x * BN, row0 = blockIdx.y * BM;
    int tid = threadIdx.x;
    int tx = tid & 15, ty = tid >> 4;
    float acc[4][4] = {{0.f}};
    int lk = tid & 15;   // k within tile
    int lr = tid >> 4;   // row/col within tile (16 per pass)
    for (int k0 = 0; k0 < K; k0 += BK) {
#pragma unroll
        for (int r = 0; r < 4; ++r) {
            int rr = lr + r * 16;
            As[lk][rr] = A[(size_t)(row0 + rr) * K + k0 + lk];
            Bs[lk][rr] = Wt[(size_t)(col0 + rr) * K + k0 + lk];
        }
        __syncthreads();
#pragma unroll
        for (int k = 0; k < BK; ++k) {
            float a[4], b[4];
#pragma unroll
            for (int i = 0; i < 4; ++i) a[i] = As[k][ty * 4 + i];
#pragma unroll
            for (int j = 0; j < 4; ++j) b[j] = Bs[k][tx * 4 + j];
#pragma unroll
            for (int i = 0; i < 4; ++i)
#pragma unroll
                for (int j = 0; j < 4; ++j) acc[i][j] += a[i] * b[j];
        }
        __syncthreads();
    }
#pragma unroll
    for (int i = 0; i < 4; ++i) {
        int row = row0 + ty * 4 + i;
#pragma unroll
        for (int j = 0; j < 4; ++j) {
            int col = col0 + tx * 4 + j;
            float v = acc[i][j] + bias[col];
            size_t oidx = (size_t)row * N + col;
            if (mode == 1) {
                v = fmaxf(v, 0.0f);
                C[oidx] = v;
            } else if (mode == 2) {
                C[oidx] = v;
                int hw = row % HWSZ, cam = row / HWSZ;
                C2[oidx] = v + e0[(size_t)hw * DD + col] + e1[(size_t)cam * DD + col];
            } else if (mode == 3) {
                C[oidx] = v + e0[oidx];
            } else {
                C[oidx] = v;
            }
        }
    }
}

// ---------------------------------------------------------------------------
// g[cam][n] = mean_hw(spc[cam]) @ conv2_w^T + conv2_b   (mean/matmul commute)
__global__ __launch_bounds__(256) void meang_kernel(const float* __restrict__ spc,
                                                    const float* __restrict__ w2,
                                                    const float* __restrict__ b2,
                                                    float* __restrict__ g) {
    int cam = blockIdx.x, t = threadIdx.x;
    __shared__ float mu[DD];
    const float* base = spc + (size_t)cam * HWSZ * DD;
    float s = 0.f;
    for (int hw = 0; hw < HWSZ; ++hw) s += base[(size_t)hw * DD + t];
    mu[t] = s * (1.0f / (float)HWSZ);
    __syncthreads();
    float acc = b2[t];
    const float* wr = w2 + (size_t)t * DD;
    for (int d = 0; d < DD; ++d) acc += mu[d] * wr[d];
    g[cam * DD + t] = acc;
}

// ---------------------------------------------------------------------------
// W_comb = conv1_w @ out_w ; b_comb = conv1_w @ out_b + conv1_b
__global__ __launch_bounds__(256) void wcomb_kernel(const float* __restrict__ conv1_w,
                                                    const float* __restrict__ out_w,
                                                    const float* __restrict__ out_b,
                                                    const float* __restrict__ conv1_b,
                                                    float* __restrict__ Wc,
                                                    float* __restrict__ bc) {
    int n = blockIdx.x, t = threadIdx.x;
    __shared__ float rowv[DD];
    rowv[t] = conv1_w[(size_t)n * DD + t];
    __syncthreads();
    float acc = 0.f;
    for (int m = 0; m < DD; ++m) acc += rowv[m] * out_w[(size_t)m * DD + t];
    Wc[(size_t)n * DD + t] = acc;
    if (t == 0) {
        float b = conv1_b[n];
        for (int m = 0; m < DD; ++m) b += rowv[m] * out_b[m];
        bc[n] = b;
    }
}

// ---------------------------------------------------------------------------
__device__ __forceinline__ float red32(float v) {
    v += __shfl_xor(v, 1);
    v += __shfl_xor(v, 2);
    v += __shfl_xor(v, 4);
    v += __shfl_xor(v, 8);
    v += __shfl_xor(v, 16);
    return v;
}

// Deformable attention core. One block per q; 8 head-groups of 32 lanes.
__global__ __launch_bounds__(256) void attn_kernel(
    const float* __restrict__ spc, const float* __restrict__ keys,
    const float* __restrict__ value, const float* __restrict__ offs,
    const float* __restrict__ g, float* __restrict__ attn_out) {
    int q = blockIdx.x;
    int tid = threadIdx.x;
    int head = tid >> 5, cc = tid & 31;
    __shared__ float soff[NHEADS * NCAM * NPOINTS * 2];  // 384
    soff[tid] = offs[(size_t)q * 384 + tid];
    if (tid < 128) soff[256 + tid] = offs[(size_t)q * 384 + 256 + tid];
    __syncthreads();
    int hw = q % HWSZ;
    int h = hw / WW, w = hw % WW;
    float rxv = ((float)w + 0.5f) / (float)WW;
    float ryv = ((float)h + 0.5f) / (float)HH;
    float qv = spc[(size_t)q * DD + head * HDIM + cc];
    float vs[NCAM * NPOINTS];
    float lg[NCAM * 5];
    float gvv[NCAM];
    const float scale = 0.17677669529663687f;  // 1/sqrt(32)
#pragma unroll
    for (int cam = 0; cam < NCAM; ++cam) {
#pragma unroll
        for (int p = 0; p < NPOINTS; ++p) {
            int ob = ((head * NCAM + cam) * NPOINTS + p) * 2;
            float ox = soff[ob], oy = soff[ob + 1];
            float lx = rxv + ox * (1.0f / (float)WW);
            float ly = ryv + oy * (1.0f / (float)HH);
            float X = lx * (float)WW - 0.5f;
            float Y = ly * (float)HH - 0.5f;
            float x0f = floorf(X), y0f = floorf(Y);
            float fx = X - x0f, fy = Y - y0f;
            int x0 = (int)x0f, y0 = (int)y0f;
            float ak = 0.f, av = 0.f;
#pragma unroll
            for (int dy = 0; dy < 2; ++dy) {
#pragma unroll
                for (int dx = 0; dx < 2; ++dx) {
                    int xi = x0 + dx, yi = y0 + dy;
                    if (xi >= 0 && xi < WW && yi >= 0 && yi < HH) {
                        float wgt = (dx ? fx : 1.0f - fx) * (dy ? fy : 1.0f - fy);
                        size_t base =
                            ((size_t)(cam * HWSZ + yi * WW + xi)) * DD + head * HDIM + cc;
                        ak += wgt * keys[base];
                        av += wgt * value[base];
                    }
                }
            }
            vs[cam * NPOINTS + p] = av;
            float l = red32(qv * ak);
            lg[cam * 5 + p] = l * scale;
        }
        float gk = g[cam * DD + head * HDIM + cc];
        gvv[cam] = gk;
        float l = red32(qv * gk);
        lg[cam * 5 + 4] = l * scale;
    }
    // softmax over the 30 logits (identical across the 32 lanes of the group)
    float m = lg[0];
#pragma unroll
    for (int i = 1; i < 30; ++i) m = fmaxf(m, lg[i]);
    float den = 0.f;
#pragma unroll
    for (int i = 0; i < 30; ++i) {
        lg[i] = __expf(lg[i] - m);
        den += lg[i];
    }
    float inv = 1.0f / den;
    float o = 0.f;
#pragma unroll
    for (int cam = 0; cam < NCAM; ++cam) {
#pragma unroll
        for (int p = 0; p < NPOINTS; ++p) o += lg[cam * 5 + p] * vs[cam * NPOINTS + p];
        o += lg[cam * 5 + 4] * gvv[cam];
    }
    attn_out[(size_t)q * DD + head * HDIM + cc] = o * inv;
}

// ---------------------------------------------------------------------------
// LayerNorm over dim=256. out = LN(a [+ b]) * gamma + beta
__global__ __launch_bounds__(256) void ln_kernel(const float* __restrict__ a,
                                                 const float* __restrict__ b,
                                                 const float* __restrict__ gamma,
                                                 const float* __restrict__ beta,
                                                 float* __restrict__ out, int addb) {
    int row = blockIdx.x, t = threadIdx.x;
    size_t idx = (size_t)row * DD + t;
    float v = a[idx];
    if (addb) v += b[idx];
    __shared__ float part[4];
    float s = v;
#pragma unroll
    for (int m = 32; m >= 1; m >>= 1) s += __shfl_xor(s, m);
    if ((t & 63) == 0) part[t >> 6] = s;
    __syncthreads();
    float mean = (part[0] + part[1] + part[2] + part[3]) * (1.0f / (float)DD);
    float d = v - mean;
    float s2 = d * d;
#pragma unroll
    for (int m = 32; m >= 1; m >>= 1) s2 += __shfl_xor(s2, m);
    __syncthreads();
    if ((t & 63) == 0) part[t >> 6] = s2;
    __syncthreads();
    float var = (part[0] + part[1] + part[2] + part[3]) * (1.0f / (float)DD);
    out[idx] = d * rsqrtf(var + 1e-5f) * gamma[t] + beta[t];
}

// ---------------------------------------------------------------------------
extern "C" void kernel_launch(void* const* d_in, const int* in_sizes, int n_in,
                              void* d_out, int out_size, void* d_ws, size_t ws_size,
                              hipStream_t stream) {
    const float* x       = (const float*)d_in[0];
    const float* conv0_w = (const float*)d_in[1];
    const float* conv0_b = (const float*)d_in[2];
    const float* conv2_w = (const float*)d_in[3];
    const float* conv2_b = (const float*)d_in[4];
    const float* cam_emb = (const float*)d_in[5];
    const float* off_w   = (const float*)d_in[6];
    const float* off_b   = (const float*)d_in[7];
    const float* val_w   = (const float*)d_in[8];
    const float* val_b   = (const float*)d_in[9];
    const float* key_w   = (const float*)d_in[10];
    const float* key_b   = (const float*)d_in[11];
    const float* out_w   = (const float*)d_in[12];
    const float* out_b   = (const float*)d_in[13];
    const float* conv1_w = (const float*)d_in[14];
    const float* conv1_b = (const float*)d_in[15];
    const float* norm0_g = (const float*)d_in[16];
    const float* norm0_b = (const float*)d_in[17];
    const float* lin1_w  = (const float*)d_in[18];
    const float* lin1_b  = (const float*)d_in[19];
    const float* lin2_w  = (const float*)d_in[20];
    const float* lin2_b  = (const float*)d_in[21];
    const float* norm2_g = (const float*)d_in[22];
    const float* norm2_b = (const float*)d_in[23];

    float* ws = (float*)d_ws;
    const size_t SZ = (size_t)LQ * DD;  // 1,228,800
    float* pos     = ws;                 // 204800
    float* xt      = pos + 204800;       // SZ
    float* src     = xt + SZ;            // SZ
    float* spc     = src + SZ;           // SZ
    float* value   = spc + SZ;           // SZ
    float* keysb   = value + SZ;         // SZ
    float* offsets = keysb + SZ;         // 4800*384
    float* g       = offsets + (size_t)LQ * 384;  // 1536
    float* wcomb   = g + NCAM * DD;      // 65536
    float* bcomb   = wcomb + DD * DD;    // 256
    float* attn_o  = bcomb + DD;         // SZ
    // aliases (lifetimes disjoint):
    float* tmp0    = src;     // comb-GEMM output (+residual); src dead after val/key
    float* out0    = value;   // post-LN0; value dead after attention
    float* hidden  = keysb;   // FFN hidden; keys dead after attention
    float* ffn     = attn_o;  // FFN out; attn_out dead after comb GEMM
    float* out_ln  = spc;     // final LN; spc dead after attention

    dim3 tgrid(25, 8, NCAM);

    pos_kernel<<<HWSZ, 256, 0, stream>>>(pos);
    transpose_in<<<tgrid, 256, 0, stream>>>(x, xt);
    // src = xt @ conv0_w^T + b ; spc = src + pos + cam_emb
    gemm_k256<<<dim3(4, 75), 256, 0, stream>>>(xt, conv0_w, conv0_b, src, 256, 2,
                                               pos, cam_emb, spc);
    meang_kernel<<<NCAM, 256, 0, stream>>>(spc, conv2_w, conv2_b, g);
    gemm_k256<<<dim3(4, 75), 256, 0, stream>>>(src, val_w, val_b, value, 256, 0,
                                               nullptr, nullptr, nullptr);
    gemm_k256<<<dim3(4, 75), 256, 0, stream>>>(src, key_w, key_b, keysb, 256, 0,
                                               nullptr, nullptr, nullptr);
    gemm_k256<<<dim3(6, 75), 256, 0, stream>>>(spc, off_w, off_b, offsets, 384, 0,
                                               nullptr, nullptr, nullptr);
    wcomb_kernel<<<DD, 256, 0, stream>>>(conv1_w, out_w, out_b, conv1_b, wcomb, bcomb);
    attn_kernel<<<LQ, 256, 0, stream>>>(spc, keysb, value, offsets, g, attn_o);
    // tmp0 = attn_o @ W_comb^T + b_comb + residual(xt)
    gemm_k256<<<dim3(4, 75), 256, 0, stream>>>(attn_o, wcomb, bcomb, tmp0, 256, 3,
                                               xt, nullptr, nullptr);
    ln_kernel<<<LQ, 256, 0, stream>>>(tmp0, nullptr, norm0_g, norm0_b, out0, 0);
    gemm_k256<<<dim3(4, 75), 256, 0, stream>>>(out0, lin1_w, lin1_b, hidden, 256, 1,
                                               nullptr, nullptr, nullptr);
    gemm_k256<<<dim3(4, 75), 256, 0, stream>>>(hidden, lin2_w, lin2_b, ffn, 256, 0,
                                               nullptr, nullptr, nullptr);
    ln_kernel<<<LQ, 256, 0, stream>>>(out0, ffn, norm2_g, norm2_b, out_ln, 1);
    transpose_out<<<tgrid, 256, 0, stream>>>(out_ln, (float*)d_out);
}

// Round 2
// 364.155 us; speedup vs baseline: 1.3087x; 1.3087x over previous
//
#include <hip/hip_runtime.h>
#include <math.h>

// Shapes (fixed by the problem)
#define NCAM 6
#define NHEADS 8
#define NPOINTS 4
#define DD 256
#define HH 20
#define WW 40
#define HWSZ 800            // H*W
#define LQ 4800             // NCAM*HWSZ
#define HDIM 32             // DD/NHEADS

// ---------------------------------------------------------------------------
// Positional encoding: pos[hw][d], d<128 -> y-enc of row, d>=128 -> x-enc of col
__global__ __launch_bounds__(256) void pos_kernel(float* __restrict__ pos) {
    int hw = blockIdx.x;       // 0..799
    int d  = threadIdx.x;      // 0..255
    int h = hw / WW, w = hw % WW;
    int j = (d & 127) >> 1;
    float t = powf(10000.0f, (float)j * (1.0f / 64.0f));
    float v;
    if (d < 128) v = (float)(h + 1) / (20.0f + 1e-6f) * (2.0f * (float)M_PI);
    else         v = (float)(w + 1) / (40.0f + 1e-6f) * (2.0f * (float)M_PI);
    float p = v / t;
    pos[hw * DD + d] = (d & 1) ? cosf(p) : sinf(p);
}

// ---------------------------------------------------------------------------
// Transpose x [6][256][800] -> xt [6][800][256]  (NCHW -> N(HW)C)
__global__ __launch_bounds__(256) void transpose_in(const float* __restrict__ x,
                                                    float* __restrict__ xt) {
    int cam = blockIdx.z;
    int hw0 = blockIdx.x * 32, c0 = blockIdx.y * 32;
    __shared__ float tile[32][33];
    int t = threadIdx.x;
    int lhw = t & 31, lc4 = t >> 5;
#pragma unroll
    for (int i = 0; i < 4; ++i) {
        int lc = lc4 * 4 + i;
        tile[lc][lhw] = x[((size_t)(cam * DD + c0 + lc)) * HWSZ + hw0 + lhw];
    }
    __syncthreads();
    int lc2 = t & 31, lhw4 = t >> 5;
#pragma unroll
    for (int i = 0; i < 4; ++i) {
        int lhw2 = lhw4 * 4 + i;
        xt[((size_t)(cam * HWSZ + hw0 + lhw2)) * DD + c0 + lc2] = tile[lc2][lhw2];
    }
}

// Transpose a [6][800][256] -> o [6][256][800]
__global__ __launch_bounds__(256) void transpose_out(const float* __restrict__ a,
                                                     float* __restrict__ o) {
    int cam = blockIdx.z;
    int hw0 = blockIdx.x * 32, c0 = blockIdx.y * 32;
    __shared__ float tile[32][33];
    int t = threadIdx.x;
    int lc = t & 31, lhw4 = t >> 5;
#pragma unroll
    for (int i = 0; i < 4; ++i) {
        int lhw = lhw4 * 4 + i;
        tile[lhw][lc] = a[((size_t)(cam * HWSZ + hw0 + lhw)) * DD + c0 + lc];
    }
    __syncthreads();
    int lhw2 = t & 31, lc4 = t >> 5;
#pragma unroll
    for (int i = 0; i < 4; ++i) {
        int lc2 = lc4 * 4 + i;
        o[((size_t)(cam * DD + c0 + lc2)) * HWSZ + hw0 + lhw2] = tile[lhw2][lc2];
    }
}

// ---------------------------------------------------------------------------
// Generic fp32 GEMM: C[M,N] = A[M,K=256] @ W[N,K]^T + bias[N]
// mode 0: plain   1: relu   2: conv0 (C=src, C2=src+pos+cam_emb)   3: C += e0
// mode 4: scatter into kvcat K slots   5: scatter into kvcat V slots
#define BM 64
#define BN 64
#define BK 16
__global__ __launch_bounds__(256) void gemm_k256(
    const float* __restrict__ A, const float* __restrict__ Wt,
    const float* __restrict__ bias, float* __restrict__ C, int N, int mode,
    const float* __restrict__ e0, const float* __restrict__ e1,
    float* __restrict__ C2) {
    const int K = 256;
    __shared__ float As[BK][BM + 4];
    __shared__ float Bs[BK][BN + 4];
    int col0 = blockIdx.x * BN, row0 = blockIdx.y * BM;
    int tid = threadIdx.x;
    int tx = tid & 15, ty = tid >> 4;
    float acc[4][4] = {{0.f}};
    int lk = tid & 15;   // k within tile
    int lr = tid >> 4;   // row/col within tile (16 per pass)
    for (int k0 = 0; k0 < K; k0 += BK) {
#pragma unroll
        for (int r = 0; r < 4; ++r) {
            int rr = lr + r * 16;
            As[lk][rr] = A[(size_t)(row0 + rr) * K + k0 + lk];
            Bs[lk][rr] = Wt[(size_t)(col0 + rr) * K + k0 + lk];
        }
        __syncthreads();
#pragma unroll
        for (int k = 0; k < BK; ++k) {
            float a[4], b[4];
#pragma unroll
            for (int i = 0; i < 4; ++i) a[i] = As[k][ty * 4 + i];
#pragma unroll
            for (int j = 0; j < 4; ++j) b[j] = Bs[k][tx * 4 + j];
#pragma unroll
            for (int i = 0; i < 4; ++i)
#pragma unroll
                for (int j = 0; j < 4; ++j) acc[i][j] += a[i] * b[j];
        }
        __syncthreads();
    }
#pragma unroll
    for (int i = 0; i < 4; ++i) {
        int row = row0 + ty * 4 + i;
#pragma unroll
        for (int j = 0; j < 4; ++j) {
            int col = col0 + tx * 4 + j;
            float v = acc[i][j] + bias[col];
            size_t oidx = (size_t)row * N + col;
            if (mode == 1) {
                v = fmaxf(v, 0.0f);
                C[oidx] = v;
            } else if (mode == 2) {
                C[oidx] = v;
                int hw = row % HWSZ, cam = row / HWSZ;
                C2[oidx] = v + e0[(size_t)hw * DD + col] + e1[(size_t)cam * DD + col];
            } else if (mode == 3) {
                C[oidx] = v + e0[oidx];
            } else if (mode == 4 || mode == 5) {
                int headc = col >> 5, c = col & 31;
                size_t kidx = ((size_t)row * 8 + headc) * 64 + c * 2 + (mode == 5 ? 1 : 0);
                C[kidx] = v;
            } else {
                C[oidx] = v;
            }
        }
    }
}

// ---------------------------------------------------------------------------
// g = mean_hw(spc) @ conv2_w^T + conv2_b   (mean/matmul commute) — 2-stage
__global__ __launch_bounds__(256) void meang1(const float* __restrict__ spc,
                                              float* __restrict__ part) {
    int cam = blockIdx.y, chunk = blockIdx.x;  // 25 chunks of 32 rows
    int t = threadIdx.x;
    const float* base = spc + ((size_t)cam * HWSZ + chunk * 32) * DD;
    float s = 0.f;
#pragma unroll 4
    for (int r = 0; r < 32; ++r) s += base[(size_t)r * DD + t];
    part[((size_t)cam * 25 + chunk) * DD + t] = s;
}

__global__ __launch_bounds__(256) void meang2(const float* __restrict__ part,
                                              const float* __restrict__ w2,
                                              const float* __restrict__ b2,
                                              float* __restrict__ g) {
    int cam = blockIdx.x, t = threadIdx.x;
    __shared__ float mu[DD];
    float s = 0.f;
    for (int c = 0; c < 25; ++c) s += part[((size_t)cam * 25 + c) * DD + t];
    mu[t] = s * (1.0f / (float)HWSZ);
    __syncthreads();
    float acc = b2[t];
    const float* wr = w2 + (size_t)t * DD;
    for (int d = 0; d < DD; ++d) acc += mu[d] * wr[d];
    g[cam * DD + t] = acc;
}

// ---------------------------------------------------------------------------
// W_comb = conv1_w @ out_w ; b_comb = conv1_w @ out_b + conv1_b
__global__ __launch_bounds__(256) void wcomb_kernel(const float* __restrict__ conv1_w,
                                                    const float* __restrict__ out_w,
                                                    const float* __restrict__ out_b,
                                                    const float* __restrict__ conv1_b,
                                                    float* __restrict__ Wc,
                                                    float* __restrict__ bc) {
    int n = blockIdx.x, t = threadIdx.x;
    __shared__ float rowv[DD];
    rowv[t] = conv1_w[(size_t)n * DD + t];
    __syncthreads();
    float acc = 0.f;
    for (int m = 0; m < DD; ++m) acc += rowv[m] * out_w[(size_t)m * DD + t];
    Wc[(size_t)n * DD + t] = acc;
    if (t == 0) {
        float b = conv1_b[n];
        for (int m = 0; m < DD; ++m) b += rowv[m] * out_b[m];
        bc[n] = b;
    }
}

// ---------------------------------------------------------------------------
__device__ __forceinline__ float red32(float v) {
    v += __shfl_xor(v, 1);
    v += __shfl_xor(v, 2);
    v += __shfl_xor(v, 4);
    v += __shfl_xor(v, 8);
    v += __shfl_xor(v, 16);
    return v;
}

__device__ __forceinline__ void upd(float& m, float& den, float& o, float l, float v) {
    float mn = fmaxf(m, l);
    float a = __expf(m - mn);
    float b = __expf(l - mn);
    den = den * a + b;
    o = o * a + b * v;
    m = mn;
}

// Deformable attention core. One block per q; 8 head-groups of 32 lanes.
// kvcat layout: [pos][head][c][2] -> idx = (pos*8+head)*64 + c*2 + {0:K,1:V}
__global__ __launch_bounds__(256, 6) void attn_kernel(
    const float* __restrict__ spc, const float* __restrict__ kvcat,
    const float* __restrict__ offs, const float* __restrict__ g,
    float* __restrict__ attn_out) {
    int q = blockIdx.x;
    int tid = threadIdx.x;
    int head = tid >> 5, cc = tid & 31;
    __shared__ float soff[NHEADS * NCAM * NPOINTS * 2];  // 384
    soff[tid] = offs[(size_t)q * 384 + tid];
    if (tid < 128) soff[256 + tid] = offs[(size_t)q * 384 + 256 + tid];
    __syncthreads();
    int hw = q % HWSZ;
    int h = hw / WW, w = hw % WW;
    float qv = spc[(size_t)q * DD + tid];
    const float scale = 0.17677669529663687f;  // 1/sqrt(32)
    float m = -1e30f, den = 0.f, o = 0.f;
    for (int cam = 0; cam < NCAM; ++cam) {
        float ak[NPOINTS], av[NPOINTS];
#pragma unroll
        for (int p = 0; p < NPOINTS; ++p) {
            int ob = ((head * NCAM + cam) * NPOINTS + p) * 2;
            // X = lx*W - 0.5 with lx = (w+0.5)/W + ox/W  ==>  X = w + ox (exact)
            float X = (float)w + soff[ob];
            float Y = (float)h + soff[ob + 1];
            float x0f = floorf(X), y0f = floorf(Y);
            float fx = X - x0f, fy = Y - y0f;
            int x0 = (int)x0f, y0 = (int)y0f;
            int x1 = x0 + 1, y1 = y0 + 1;
            float vx0 = (x0 >= 0 && x0 < WW) ? 1.f : 0.f;
            float vx1 = (x1 >= 0 && x1 < WW) ? 1.f : 0.f;
            float vy0 = (y0 >= 0 && y0 < HH) ? 1.f : 0.f;
            float vy1 = (y1 >= 0 && y1 < HH) ? 1.f : 0.f;
            int cx0 = min(max(x0, 0), WW - 1), cx1 = min(max(x1, 0), WW - 1);
            int cy0 = min(max(y0, 0), HH - 1), cy1 = min(max(y1, 0), HH - 1);
            float w00 = (1.f - fx) * (1.f - fy) * vx0 * vy0;
            float w10 = fx * (1.f - fy) * vx1 * vy0;
            float w01 = (1.f - fx) * fy * vx0 * vy1;
            float w11 = fx * fy * vx1 * vy1;
            size_t hb = (size_t)head * 64 + (size_t)cc * 2;
            const float* b00 = kvcat + (size_t)((cam * HWSZ + cy0 * WW + cx0) * 8) * 64 + hb;
            const float* b10 = kvcat + (size_t)((cam * HWSZ + cy0 * WW + cx1) * 8) * 64 + hb;
            const float* b01 = kvcat + (size_t)((cam * HWSZ + cy1 * WW + cx0) * 8) * 64 + hb;
            const float* b11 = kvcat + (size_t)((cam * HWSZ + cy1 * WW + cx1) * 8) * 64 + hb;
            float2 s00 = *(const float2*)b00;
            float2 s10 = *(const float2*)b10;
            float2 s01 = *(const float2*)b01;
            float2 s11 = *(const float2*)b11;
            ak[p] = w00 * s00.x + w10 * s10.x + w01 * s01.x + w11 * s11.x;
            av[p] = w00 * s00.y + w10 * s10.y + w01 * s01.y + w11 * s11.y;
        }
        float lg[NPOINTS];
#pragma unroll
        for (int p = 0; p < NPOINTS; ++p) lg[p] = red32(qv * ak[p]) * scale;
        float gk = g[cam * DD + tid];
        float lgg = red32(qv * gk) * scale;
#pragma unroll
        for (int p = 0; p < NPOINTS; ++p) upd(m, den, o, lg[p], av[p]);
        upd(m, den, o, lgg, gk);
    }
    attn_out[(size_t)q * DD + tid] = o / den;
}

// ---------------------------------------------------------------------------
// LayerNorm over dim=256. out = LN(a [+ b]) * gamma + beta
__global__ __launch_bounds__(256) void ln_kernel(const float* __restrict__ a,
                                                 const float* __restrict__ b,
                                                 const float* __restrict__ gamma,
                                                 const float* __restrict__ beta,
                                                 float* __restrict__ out, int addb) {
    int row = blockIdx.x, t = threadIdx.x;
    size_t idx = (size_t)row * DD + t;
    float v = a[idx];
    if (addb) v += b[idx];
    __shared__ float part[4];
    float s = v;
#pragma unroll
    for (int m = 32; m >= 1; m >>= 1) s += __shfl_xor(s, m);
    if ((t & 63) == 0) part[t >> 6] = s;
    __syncthreads();
    float mean = (part[0] + part[1] + part[2] + part[3]) * (1.0f / (float)DD);
    float d = v - mean;
    float s2 = d * d;
#pragma unroll
    for (int m = 32; m >= 1; m >>= 1) s2 += __shfl_xor(s2, m);
    __syncthreads();
    if ((t & 63) == 0) part[t >> 6] = s2;
    __syncthreads();
    float var = (part[0] + part[1] + part[2] + part[3]) * (1.0f / (float)DD);
    out[idx] = d * rsqrtf(var + 1e-5f) * gamma[t] + beta[t];
}

// ---------------------------------------------------------------------------
extern "C" void kernel_launch(void* const* d_in, const int* in_sizes, int n_in,
                              void* d_out, int out_size, void* d_ws, size_t ws_size,
                              hipStream_t stream) {
    const float* x       = (const float*)d_in[0];
    const float* conv0_w = (const float*)d_in[1];
    const float* conv0_b = (const float*)d_in[2];
    const float* conv2_w = (const float*)d_in[3];
    const float* conv2_b = (const float*)d_in[4];
    const float* cam_emb = (const float*)d_in[5];
    const float* off_w   = (const float*)d_in[6];
    const float* off_b   = (const float*)d_in[7];
    const float* val_w   = (const float*)d_in[8];
    const float* val_b   = (const float*)d_in[9];
    const float* key_w   = (const float*)d_in[10];
    const float* key_b   = (const float*)d_in[11];
    const float* out_w   = (const float*)d_in[12];
    const float* out_b   = (const float*)d_in[13];
    const float* conv1_w = (const float*)d_in[14];
    const float* conv1_b = (const float*)d_in[15];
    const float* norm0_g = (const float*)d_in[16];
    const float* norm0_b = (const float*)d_in[17];
    const float* lin1_w  = (const float*)d_in[18];
    const float* lin1_b  = (const float*)d_in[19];
    const float* lin2_w  = (const float*)d_in[20];
    const float* lin2_b  = (const float*)d_in[21];
    const float* norm2_g = (const float*)d_in[22];
    const float* norm2_b = (const float*)d_in[23];

    float* ws = (float*)d_ws;
    const size_t SZ = (size_t)LQ * DD;  // 1,228,800
    float* pos     = ws;                          // 204800
    float* xt      = pos + 204800;                // SZ
    float* src     = xt + SZ;                     // SZ
    float* spc     = src + SZ;                    // SZ
    float* kvcat   = spc + SZ;                    // 2*SZ  (interleaved K/V)
    float* offsets = kvcat + 2 * SZ;              // 4800*384
    float* g       = offsets + (size_t)LQ * 384;  // 1536
    float* part    = g + NCAM * DD;               // 6*25*256
    float* wcomb   = part + 38400;                // 65536
    float* bcomb   = wcomb + DD * DD;             // 256
    float* attn_o  = bcomb + DD;                  // SZ
    // aliases (lifetimes disjoint):
    float* tmp0    = src;      // comb-GEMM output; src dead after key/val GEMMs
    float* out0    = offsets;  // post-LN0; offsets dead after attention
    float* hidden  = kvcat;    // FFN hidden; kvcat dead after attention
    float* ffn     = attn_o;   // FFN out; attn_o dead after comb GEMM
    float* out_ln  = spc;      // final LN; spc dead after attention

    dim3 tgrid(25, 8, NCAM);

    pos_kernel<<<HWSZ, 256, 0, stream>>>(pos);
    transpose_in<<<tgrid, 256, 0, stream>>>(x, xt);
    // src = xt @ conv0_w^T + b ; spc = src + pos + cam_emb
    gemm_k256<<<dim3(4, 75), 256, 0, stream>>>(xt, conv0_w, conv0_b, src, 256, 2,
                                               pos, cam_emb, spc);
    meang1<<<dim3(25, NCAM), 256, 0, stream>>>(spc, part);
    meang2<<<NCAM, 256, 0, stream>>>(part, conv2_w, conv2_b, g);
    gemm_k256<<<dim3(4, 75), 256, 0, stream>>>(src, key_w, key_b, kvcat, 256, 4,
                                               nullptr, nullptr, nullptr);
    gemm_k256<<<dim3(4, 75), 256, 0, stream>>>(src, val_w, val_b, kvcat, 256, 5,
                                               nullptr, nullptr, nullptr);
    gemm_k256<<<dim3(6, 75), 256, 0, stream>>>(spc, off_w, off_b, offsets, 384, 0,
                                               nullptr, nullptr, nullptr);
    wcomb_kernel<<<DD, 256, 0, stream>>>(conv1_w, out_w, out_b, conv1_b, wcomb, bcomb);
    attn_kernel<<<LQ, 256, 0, stream>>>(spc, kvcat, offsets, g, attn_o);
    // tmp0 = attn_o @ W_comb^T + b_comb + residual(xt)
    gemm_k256<<<dim3(4, 75), 256, 0, stream>>>(attn_o, wcomb, bcomb, tmp0, 256, 3,
                                               xt, nullptr, nullptr);
    ln_kernel<<<LQ, 256, 0, stream>>>(tmp0, nullptr, norm0_g, norm0_b, out0, 0);
    gemm_k256<<<dim3(4, 75), 256, 0, stream>>>(out0, lin1_w, lin1_b, hidden, 256, 1,
                                               nullptr, nullptr, nullptr);
    gemm_k256<<<dim3(4, 75), 256, 0, stream>>>(hidden, lin2_w, lin2_b, ffn, 256, 0,
                                               nullptr, nullptr, nullptr);
    ln_kernel<<<LQ, 256, 0, stream>>>(out0, ffn, norm2_g, norm2_b, out_ln, 1);
    transpose_out<<<tgrid, 256, 0, stream>>>(out_ln, (float*)d_out);
}

// Round 3
// 267.524 us; speedup vs baseline: 1.7814x; 1.3612x over previous
//
#include <hip/hip_runtime.h>
#include <math.h>

typedef unsigned short u16;
typedef unsigned int u32;

// Shapes (fixed by the problem)
#define NCAM 6
#define NHEADS 8
#define NPOINTS 4
#define DD 256
#define HH 20
#define WW 40
#define HWSZ 800            // H*W
#define LQ 4800             // NCAM*HWSZ
#define HDIM 32             // DD/NHEADS

typedef __attribute__((ext_vector_type(8))) short bf16x8;
typedef __attribute__((ext_vector_type(4))) float f32x4;

__device__ __forceinline__ u16 f2b(float x) {
    union { float f; u32 u; } v;
    v.f = x;
    u32 r = (v.u + 0x7FFFu + ((v.u >> 16) & 1u)) >> 16;  // RNE
    return (u16)r;
}

// ---------------------------------------------------------------------------
// Positional encoding: pos[hw][d], d<128 -> y-enc of row, d>=128 -> x-enc of col
__global__ __launch_bounds__(256) void pos_kernel(float* __restrict__ pos) {
    int hw = blockIdx.x;       // 0..799
    int d  = threadIdx.x;      // 0..255
    int h = hw / WW, w = hw % WW;
    int j = (d & 127) >> 1;
    float t = powf(10000.0f, (float)j * (1.0f / 64.0f));
    float v;
    if (d < 128) v = (float)(h + 1) / (20.0f + 1e-6f) * (2.0f * (float)M_PI);
    else         v = (float)(w + 1) / (40.0f + 1e-6f) * (2.0f * (float)M_PI);
    float p = v / t;
    pos[hw * DD + d] = (d & 1) ? cosf(p) : sinf(p);
}

// ---------------------------------------------------------------------------
// Transpose x [6][256][800] -> xt fp32 [6][800][256] + xtb bf16 (GEMM A input)
__global__ __launch_bounds__(256) void transpose_in(const float* __restrict__ x,
                                                    float* __restrict__ xt,
                                                    u16* __restrict__ xtb) {
    int cam = blockIdx.z;
    int hw0 = blockIdx.x * 32, c0 = blockIdx.y * 32;
    __shared__ float tile[32][33];
    int t = threadIdx.x;
    int lhw = t & 31, lc4 = t >> 5;
#pragma unroll
    for (int i = 0; i < 4; ++i) {
        int lc = lc4 * 4 + i;
        tile[lc][lhw] = x[((size_t)(cam * DD + c0 + lc)) * HWSZ + hw0 + lhw];
    }
    __syncthreads();
    int lc2 = t & 31, lhw4 = t >> 5;
#pragma unroll
    for (int i = 0; i < 4; ++i) {
        int lhw2 = lhw4 * 4 + i;
        float v = tile[lc2][lhw2];
        size_t idx = ((size_t)(cam * HWSZ + hw0 + lhw2)) * DD + c0 + lc2;
        xt[idx] = v;
        xtb[idx] = f2b(v);
    }
}

// Transpose a [6][800][256] -> o [6][256][800]
__global__ __launch_bounds__(256) void transpose_out(const float* __restrict__ a,
                                                     float* __restrict__ o) {
    int cam = blockIdx.z;
    int hw0 = blockIdx.x * 32, c0 = blockIdx.y * 32;
    __shared__ float tile[32][33];
    int t = threadIdx.x;
    int lc = t & 31, lhw4 = t >> 5;
#pragma unroll
    for (int i = 0; i < 4; ++i) {
        int lhw = lhw4 * 4 + i;
        tile[lhw][lc] = a[((size_t)(cam * HWSZ + hw0 + lhw)) * DD + c0 + lc];
    }
    __syncthreads();
    int lhw2 = t & 31, lc4 = t >> 5;
#pragma unroll
    for (int i = 0; i < 4; ++i) {
        int lc2 = lc4 * 4 + i;
        o[((size_t)(cam * DD + c0 + lc2)) * HWSZ + hw0 + lhw2] = tile[lhw2][lc2];
    }
}

// ---------------------------------------------------------------------------
// Weight prep: fp32 -> bf16 for conv0/off/lin1/lin2 + interleave-packed KV.
// wb layout: [0,65536)=conv0  [65536,196608)=kv(512x256)  [196608,294912)=off
//            [294912,360448)=lin1  [360448,425984)=lin2
__global__ __launch_bounds__(256) void prep_weights(
    const float* __restrict__ conv0_w, const float* __restrict__ key_w,
    const float* __restrict__ key_b, const float* __restrict__ val_w,
    const float* __restrict__ val_b, const float* __restrict__ off_w,
    const float* __restrict__ lin1_w, const float* __restrict__ lin2_w,
    u16* __restrict__ wb, float* __restrict__ bkv) {
    int i = blockIdx.x * 256 + threadIdx.x;  // < 425984
    float v;
    if (i < 65536) {
        v = conv0_w[i];
    } else if (i < 196608) {
        int j = i - 65536;
        int rowj = j >> 8, k = j & 255;
        int head = rowj >> 6, c = (rowj & 63) >> 1, kv = rowj & 1;
        const float* wsrc = kv ? val_w : key_w;
        v = wsrc[(size_t)(head * 32 + c) * 256 + k];
        if (k == 0) bkv[rowj] = (kv ? val_b : key_b)[head * 32 + c];
    } else if (i < 294912) {
        v = off_w[i - 196608];
    } else if (i < 360448) {
        v = lin1_w[i - 294912];
    } else {
        v = lin2_w[i - 360448];
    }
    wb[i] = f2b(v);
}

// ---------------------------------------------------------------------------
// W_comb = conv1_w @ out_w (bf16 out) ; b_comb = conv1_w @ out_b + conv1_b
__global__ __launch_bounds__(256) void wcomb_kernel(const float* __restrict__ conv1_w,
                                                    const float* __restrict__ out_w,
                                                    const float* __restrict__ out_b,
                                                    const float* __restrict__ conv1_b,
                                                    u16* __restrict__ Wc,
                                                    float* __restrict__ bc) {
    int n = blockIdx.x, t = threadIdx.x;
    __shared__ float rowv[DD];
    rowv[t] = conv1_w[(size_t)n * DD + t];
    __syncthreads();
    float acc = 0.f;
    for (int m = 0; m < DD; ++m) acc += rowv[m] * out_w[(size_t)m * DD + t];
    Wc[(size_t)n * DD + t] = f2b(acc);
    if (t == 0) {
        float b = conv1_b[n];
        for (int m = 0; m < DD; ++m) b += rowv[m] * out_b[m];
        bc[n] = b;
    }
}

// ---------------------------------------------------------------------------
// bf16 MFMA GEMM: C[M,N] = Ab[M,256](bf16) @ Wb[N,256](bf16)^T + bias.
// BM=32, BN=128, 4 waves; wave w covers cols [w*32, w*32+32).
// LDS layout [kgroup j][row][8bf16] (+1 row pad per j) -> aligned b128, no conflicts.
// mode 0: C=v (fp32)        1: Cb=bf16(relu(v))
// mode 2: Cb=bf16(v); s=v+e0[hw]+e1[cam]; C=s; Cb2=bf16(s)   (conv0)
// mode 3: C=v+e0 (residual)
__global__ __launch_bounds__(256) void gemm_bf16(
    const u16* __restrict__ Ab, const u16* __restrict__ Wb,
    const float* __restrict__ bias, float* __restrict__ C,
    u16* __restrict__ Cb, u16* __restrict__ Cb2, int N, int mode,
    const float* __restrict__ e0, const float* __restrict__ e1) {
    __shared__ __align__(16) u16 As[1056];   // (3*33+31)*8+8
    __shared__ __align__(16) u16 Bs[4120];   // (3*129+127)*8+8
    int t = threadIdx.x;
    int col0 = blockIdx.x * 128, row0 = blockIdx.y * 32;
    int wv = t >> 6, lane = t & 63;
    int quad = lane >> 4, l = lane & 15;
    f32x4 acc[2][2] = {};
    for (int k0 = 0; k0 < 256; k0 += 32) {
        __syncthreads();
        if (t < 128) {
            int m = t >> 2, j = t & 3;
            *(uint4*)&As[(j * 33 + m) * 8] =
                *(const uint4*)&Ab[(size_t)(row0 + m) * 256 + k0 + j * 8];
        }
        {
            int n = t >> 1, jp = (t & 1) * 2;
            const u16* gsrc = &Wb[(size_t)(col0 + n) * 256 + k0 + jp * 8];
            *(uint4*)&Bs[(jp * 129 + n) * 8]       = *(const uint4*)gsrc;
            *(uint4*)&Bs[((jp + 1) * 129 + n) * 8] = *(const uint4*)(gsrc + 8);
        }
        __syncthreads();
        bf16x8 a0 = *(const bf16x8*)&As[(quad * 33 + l) * 8];
        bf16x8 a1 = *(const bf16x8*)&As[(quad * 33 + 16 + l) * 8];
        bf16x8 b0 = *(const bf16x8*)&Bs[(quad * 129 + wv * 32 + l) * 8];
        bf16x8 b1 = *(const bf16x8*)&Bs[(quad * 129 + wv * 32 + 16 + l) * 8];
        acc[0][0] = __builtin_amdgcn_mfma_f32_16x16x32_bf16(a0, b0, acc[0][0], 0, 0, 0);
        acc[0][1] = __builtin_amdgcn_mfma_f32_16x16x32_bf16(a0, b1, acc[0][1], 0, 0, 0);
        acc[1][0] = __builtin_amdgcn_mfma_f32_16x16x32_bf16(a1, b0, acc[1][0], 0, 0, 0);
        acc[1][1] = __builtin_amdgcn_mfma_f32_16x16x32_bf16(a1, b1, acc[1][1], 0, 0, 0);
    }
#pragma unroll
    for (int mt = 0; mt < 2; ++mt) {
#pragma unroll
        for (int nt = 0; nt < 2; ++nt) {
            int col = col0 + wv * 32 + nt * 16 + l;
            float bb = bias[col];
#pragma unroll
            for (int r = 0; r < 4; ++r) {
                int row = row0 + mt * 16 + quad * 4 + r;
                float v = acc[mt][nt][r] + bb;
                size_t oi = (size_t)row * N + col;
                if (mode == 0) {
                    C[oi] = v;
                } else if (mode == 1) {
                    Cb[oi] = f2b(fmaxf(v, 0.f));
                } else if (mode == 2) {
                    Cb[oi] = f2b(v);
                    int cam = row / HWSZ, hw = row % HWSZ;
                    float s = v + e0[(size_t)hw * DD + col] + e1[(size_t)cam * DD + col];
                    C[oi] = s;
                    Cb2[oi] = f2b(s);
                } else {  // mode 3
                    C[oi] = v + e0[oi];
                }
            }
        }
    }
}

// ---------------------------------------------------------------------------
// g = mean_hw(spc) @ conv2_w^T + conv2_b   (mean/matmul commute) — 2-stage
__global__ __launch_bounds__(256) void meang1(const float* __restrict__ spc,
                                              float* __restrict__ part) {
    int cam = blockIdx.y, chunk = blockIdx.x;  // 25 chunks of 32 rows
    int t = threadIdx.x;
    const float* base = spc + ((size_t)cam * HWSZ + chunk * 32) * DD;
    float s = 0.f;
#pragma unroll 4
    for (int r = 0; r < 32; ++r) s += base[(size_t)r * DD + t];
    part[((size_t)cam * 25 + chunk) * DD + t] = s;
}

__global__ __launch_bounds__(256) void meang2(const float* __restrict__ part,
                                              const float* __restrict__ w2,
                                              const float* __restrict__ b2,
                                              float* __restrict__ g) {
    int cam = blockIdx.x, t = threadIdx.x;
    __shared__ float mu[DD];
    float s = 0.f;
    for (int c = 0; c < 25; ++c) s += part[((size_t)cam * 25 + c) * DD + t];
    mu[t] = s * (1.0f / (float)HWSZ);
    __syncthreads();
    float acc = b2[t];
    const float* wr = w2 + (size_t)t * DD;
    for (int d = 0; d < DD; ++d) acc += mu[d] * wr[d];
    g[cam * DD + t] = acc;
}

// ---------------------------------------------------------------------------
__device__ __forceinline__ float red32(float v) {
    v += __shfl_xor(v, 1);
    v += __shfl_xor(v, 2);
    v += __shfl_xor(v, 4);
    v += __shfl_xor(v, 8);
    v += __shfl_xor(v, 16);
    return v;
}

__device__ __forceinline__ void upd(float& m, float& den, float& o, float l, float v) {
    float mn = fmaxf(m, l);
    float a = __expf(m - mn);
    float b = __expf(l - mn);
    den = den * a + b;
    o = o * a + b * v;
    m = mn;
}

// Deformable attention core. One block per q; 8 head-groups of 32 lanes.
// kvcat layout: [pos][head][c][2] -> idx = pos*512 + head*64 + c*2 + {0:K,1:V}
__global__ __launch_bounds__(256, 6) void attn_kernel(
    const float* __restrict__ spc, const float* __restrict__ kvcat,
    const float* __restrict__ offs, const float* __restrict__ g,
    u16* __restrict__ attn_out) {
    int q = blockIdx.x;
    int tid = threadIdx.x;
    int head = tid >> 5, cc = tid & 31;
    __shared__ float soff[NHEADS * NCAM * NPOINTS * 2];  // 384
    soff[tid] = offs[(size_t)q * 384 + tid];
    if (tid < 128) soff[256 + tid] = offs[(size_t)q * 384 + 256 + tid];
    __syncthreads();
    int hw = q % HWSZ;
    int h = hw / WW, w = hw % WW;
    float qv = spc[(size_t)q * DD + tid];
    const float scale = 0.17677669529663687f;  // 1/sqrt(32)
    float m = -1e30f, den = 0.f, o = 0.f;
    for (int cam = 0; cam < NCAM; ++cam) {
        float ak[NPOINTS], av[NPOINTS];
#pragma unroll
        for (int p = 0; p < NPOINTS; ++p) {
            int ob = ((head * NCAM + cam) * NPOINTS + p) * 2;
            // X = lx*W - 0.5 with lx = (w+0.5)/W + ox/W  ==>  X = w + ox (exact)
            float X = (float)w + soff[ob];
            float Y = (float)h + soff[ob + 1];
            float x0f = floorf(X), y0f = floorf(Y);
            float fx = X - x0f, fy = Y - y0f;
            int x0 = (int)x0f, y0 = (int)y0f;
            int x1 = x0 + 1, y1 = y0 + 1;
            float vx0 = (x0 >= 0 && x0 < WW) ? 1.f : 0.f;
            float vx1 = (x1 >= 0 && x1 < WW) ? 1.f : 0.f;
            float vy0 = (y0 >= 0 && y0 < HH) ? 1.f : 0.f;
            float vy1 = (y1 >= 0 && y1 < HH) ? 1.f : 0.f;
            int cx0 = min(max(x0, 0), WW - 1), cx1 = min(max(x1, 0), WW - 1);
            int cy0 = min(max(y0, 0), HH - 1), cy1 = min(max(y1, 0), HH - 1);
            float w00 = (1.f - fx) * (1.f - fy) * vx0 * vy0;
            float w10 = fx * (1.f - fy) * vx1 * vy0;
            float w01 = (1.f - fx) * fy * vx0 * vy1;
            float w11 = fx * fy * vx1 * vy1;
            size_t hb = (size_t)head * 64 + (size_t)cc * 2;
            const float* b00 = kvcat + (size_t)((cam * HWSZ + cy0 * WW + cx0) * 8) * 64 + hb;
            const float* b10 = kvcat + (size_t)((cam * HWSZ + cy0 * WW + cx1) * 8) * 64 + hb;
            const float* b01 = kvcat + (size_t)((cam * HWSZ + cy1 * WW + cx0) * 8) * 64 + hb;
            const float* b11 = kvcat + (size_t)((cam * HWSZ + cy1 * WW + cx1) * 8) * 64 + hb;
            float2 s00 = *(const float2*)b00;
            float2 s10 = *(const float2*)b10;
            float2 s01 = *(const float2*)b01;
            float2 s11 = *(const float2*)b11;
            ak[p] = w00 * s00.x + w10 * s10.x + w01 * s01.x + w11 * s11.x;
            av[p] = w00 * s00.y + w10 * s10.y + w01 * s01.y + w11 * s11.y;
        }
        float lg[NPOINTS];
#pragma unroll
        for (int p = 0; p < NPOINTS; ++p) lg[p] = red32(qv * ak[p]) * scale;
        float gk = g[cam * DD + tid];
        float lgg = red32(qv * gk) * scale;
#pragma unroll
        for (int p = 0; p < NPOINTS; ++p) upd(m, den, o, lg[p], av[p]);
        upd(m, den, o, lgg, gk);
    }
    attn_out[(size_t)q * DD + tid] = f2b(o / den);
}

// ---------------------------------------------------------------------------
// LayerNorm over dim=256. out = LN(a [+ b]) * gamma + beta (+ bf16 copy)
__global__ __launch_bounds__(256) void ln_kernel(const float* __restrict__ a,
                                                 const float* __restrict__ b,
                                                 const float* __restrict__ gamma,
                                                 const float* __restrict__ beta,
                                                 float* __restrict__ out,
                                                 u16* __restrict__ outb, int addb) {
    int row = blockIdx.x, t = threadIdx.x;
    size_t idx = (size_t)row * DD + t;
    float v = a[idx];
    if (addb) v += b[idx];
    __shared__ float part[4];
    float s = v;
#pragma unroll
    for (int m = 32; m >= 1; m >>= 1) s += __shfl_xor(s, m);
    if ((t & 63) == 0) part[t >> 6] = s;
    __syncthreads();
    float mean = (part[0] + part[1] + part[2] + part[3]) * (1.0f / (float)DD);
    float d = v - mean;
    float s2 = d * d;
#pragma unroll
    for (int m = 32; m >= 1; m >>= 1) s2 += __shfl_xor(s2, m);
    __syncthreads();
    if ((t & 63) == 0) part[t >> 6] = s2;
    __syncthreads();
    float var = (part[0] + part[1] + part[2] + part[3]) * (1.0f / (float)DD);
    float res = d * rsqrtf(var + 1e-5f) * gamma[t] + beta[t];
    if (out) out[idx] = res;
    if (outb) outb[idx] = f2b(res);
}

// ---------------------------------------------------------------------------
extern "C" void kernel_launch(void* const* d_in, const int* in_sizes, int n_in,
                              void* d_out, int out_size, void* d_ws, size_t ws_size,
                              hipStream_t stream) {
    const float* x       = (const float*)d_in[0];
    const float* conv0_w = (const float*)d_in[1];
    const float* conv0_b = (const float*)d_in[2];
    const float* conv2_w = (const float*)d_in[3];
    const float* conv2_b = (const float*)d_in[4];
    const float* cam_emb = (const float*)d_in[5];
    const float* off_w   = (const float*)d_in[6];
    const float* off_b   = (const float*)d_in[7];
    const float* val_w   = (const float*)d_in[8];
    const float* val_b   = (const float*)d_in[9];
    const float* key_w   = (const float*)d_in[10];
    const float* key_b   = (const float*)d_in[11];
    const float* out_w   = (const float*)d_in[12];
    const float* out_b   = (const float*)d_in[13];
    const float* conv1_w = (const float*)d_in[14];
    const float* conv1_b = (const float*)d_in[15];
    const float* norm0_g = (const float*)d_in[16];
    const float* norm0_b = (const float*)d_in[17];
    const float* lin1_w  = (const float*)d_in[18];
    const float* lin1_b  = (const float*)d_in[19];
    const float* lin2_w  = (const float*)d_in[20];
    const float* lin2_b  = (const float*)d_in[21];
    const float* norm2_g = (const float*)d_in[22];
    const float* norm2_b = (const float*)d_in[23];

    float* ws = (float*)d_ws;
    const size_t SZ = (size_t)LQ * DD;  // 1,228,800
    float* pos     = ws;                            // 204800
    float* xt      = pos + 204800;                  // SZ (fp32 residual)
    u16*   xtb     = (u16*)(xt + SZ);               // SZ u16 (614400 f)
    float* spc     = xt + SZ + SZ / 2;              // SZ
    u16*   srcb    = (u16*)(spc + SZ);              // SZ u16
    u16*   spcb    = (u16*)(spc + SZ + SZ / 2);     // SZ u16
    float* kvcat   = spc + 2 * SZ;                  // 2*SZ
    float* offsets = kvcat + 2 * SZ;                // LQ*384 = 1,843,200
    float* g       = offsets + (size_t)LQ * 384;    // 1536
    float* part    = g + NCAM * DD;                 // 38400
    u16*   wcombb  = (u16*)(part + 38400);          // 65536 u16 (32768 f)
    float* bcomb   = part + 38400 + 32768;          // 256
    u16*   wb      = (u16*)(bcomb + 256);           // 425984 u16 (212992 f)
    float* bkv     = bcomb + 256 + 212992;          // 512
    // aliases (lifetimes disjoint):
    float* tmp0    = (float*)srcb;        // SZ fp32 over srcb+spcb (dead by then)
    u16*   attn_ob = xtb;                 // xtb dead after conv0 GEMM
    float* out0    = offsets;             // offsets dead after attention
    u16*   out0b   = (u16*)(offsets + SZ);
    u16*   hidden  = (u16*)kvcat;         // kvcat dead after attention
    float* ffn     = kvcat + SZ / 2;
    float* out_ln  = spc;                 // spc dead after attention

    dim3 tgrid(25, 8, NCAM);

    pos_kernel<<<HWSZ, 256, 0, stream>>>(pos);
    transpose_in<<<tgrid, 256, 0, stream>>>(x, xt, xtb);
    prep_weights<<<1664, 256, 0, stream>>>(conv0_w, key_w, key_b, val_w, val_b,
                                           off_w, lin1_w, lin2_w, wb, bkv);
    wcomb_kernel<<<DD, 256, 0, stream>>>(conv1_w, out_w, out_b, conv1_b, wcombb, bcomb);
    // conv0: srcb=bf16(src); spc=src+pos+cam (fp32); spcb=bf16(spc)
    gemm_bf16<<<dim3(2, 150), 256, 0, stream>>>(xtb, wb, conv0_b, spc, srcb, spcb,
                                                256, 2, pos, cam_emb);
    meang1<<<dim3(25, NCAM), 256, 0, stream>>>(spc, part);
    meang2<<<NCAM, 256, 0, stream>>>(part, conv2_w, conv2_b, g);
    // fused key+val -> kvcat (N=512, packed interleaved weights)
    gemm_bf16<<<dim3(4, 150), 256, 0, stream>>>(srcb, wb + 65536, bkv, kvcat,
                                                nullptr, nullptr, 512, 0, nullptr, nullptr);
    gemm_bf16<<<dim3(3, 150), 256, 0, stream>>>(spcb, wb + 196608, off_b, offsets,
                                                nullptr, nullptr, 384, 0, nullptr, nullptr);
    attn_kernel<<<LQ, 256, 0, stream>>>(spc, kvcat, offsets, g, attn_ob);
    // tmp0 = attn_o @ W_comb^T + b_comb + residual(xt)
    gemm_bf16<<<dim3(2, 150), 256, 0, stream>>>(attn_ob, wcombb, bcomb, tmp0,
                                                nullptr, nullptr, 256, 3, xt, nullptr);
    ln_kernel<<<LQ, 256, 0, stream>>>(tmp0, nullptr, norm0_g, norm0_b, out0, out0b, 0);
    gemm_bf16<<<dim3(2, 150), 256, 0, stream>>>(out0b, wb + 294912, lin1_b, nullptr,
                                                hidden, nullptr, 256, 1, nullptr, nullptr);
    gemm_bf16<<<dim3(2, 150), 256, 0, stream>>>(hidden, wb + 360448, lin2_b, ffn,
                                                nullptr, nullptr, 256, 0, nullptr, nullptr);
    ln_kernel<<<LQ, 256, 0, stream>>>(out0, ffn, norm2_g, norm2_b, out_ln, nullptr, 1);
    transpose_out<<<tgrid, 256, 0, stream>>>(out_ln, (float*)d_out);
}